// Round 3
// baseline (122.582 us; speedup 1.0000x reference)
//
#include <hip/hip_runtime.h>
#include <hip/hip_cooperative_groups.h>

namespace cg = cooperative_groups;

// Problem constants (B, N, F, O) = (4, 4096, 64, 64)
#define Bq 4
#define Nq 4096
#define Fq 64
#define Oq 64

// Single fused cooperative kernel, 64 blocks x 256 threads (co-resident on
// 256 CUs). Block k owns global rows [k*256, (k+1)*256) in ALL phases, so
// its phase-2 x re-read hits the same XCD's L2.
//
// ws float layout: s_row[16384] | s_col[16384] | blocksum[64] |
//                  pxd[64*64] | pxsd[64*64]
__global__ __launch_bounds__(256) void gcn_fused(
    const float* __restrict__ x, const float* __restrict__ adj_w,
    const float* __restrict__ adj_bp, const float* __restrict__ weight,
    const float* __restrict__ bias, float* __restrict__ out,
    float* __restrict__ ws) {
  float* s_row = ws;
  float* s_col = ws + Bq * Nq;
  float* blocksum = ws + 2 * Bq * Nq;
  float* pxd = blocksum + 64;
  float* pxsd = pxd + 64 * 64;

  cg::grid_group grid = cg::this_grid();
  const int k = blockIdx.x;  // 0..63
  const int t = threadIdx.x;
  const int b = k >> 4;  // batch (16 blocks per batch)
  const float adj_b = adj_bp[0];

  __shared__ float red[2][4][64];  // phase-1 flat[256] reduce, phase-2 reduce
  __shared__ float uv[4][64];      // xdl, xsdl, u, v

  // ---- Phase 1: per-row dots (thread t owns row k*256+t) ----
  {
    int r = k * 256 + t;
    const float4* xr = reinterpret_cast<const float4*>(x + (size_t)r * Fq);
    const float4* w0 = reinterpret_cast<const float4*>(adj_w);
    const float4* w1 = reinterpret_cast<const float4*>(adj_w + Fq);
    float sc = 0.f, sr = 0.f;
#pragma unroll
    for (int q = 0; q < Fq / 4; ++q) {
      float4 v = xr[q];
      float4 a = w0[q];
      float4 c = w1[q];
      sc += v.x * a.x + v.y * a.y + v.z * a.z + v.w * a.w;
      sr += v.x * c.x + v.y * c.y + v.z * c.z + v.w * c.w;
    }
    s_col[r] = sc;
    s_row[r] = sr;
    float* redf = &red[0][0][0];
    redf[t] = sc;
    __syncthreads();
    for (int s = 128; s > 0; s >>= 1) {
      if (t < s) redf[t] += redf[t + s];
      __syncthreads();
    }
    if (t == 0) blocksum[k] = redf[0];
  }
  __threadfence();
  grid.sync();

  // ---- Phase 2: per-block partials of xd/xsd over this block's 256 j's ----
  float scs = 0.f;
#pragma unroll
  for (int c = 0; c < 16; ++c) scs += blocksum[b * 16 + c];
  {
    int f = t & 63;
    int jsub = t >> 6;  // 0..3
    float axd = 0.f, axsd = 0.f;
    int row0 = k * 256;
    for (int j = jsub; j < 256; j += 4) {
      int row = row0 + j;
      float srj = s_row[row];
      float scj = s_col[row];
      float dj = rsqrtf(fmaxf(fmaf((float)Nq, srj + adj_b, scs), 1.0f));
      float xv = x[(size_t)row * Fq + f];
      axd = fmaf(dj, xv, axd);
      axsd = fmaf(scj * dj, xv, axsd);
    }
    __syncthreads();  // red was used in phase 1
    red[0][jsub][f] = axd;
    red[1][jsub][f] = axsd;
    __syncthreads();
    if (t < 64) {
      pxd[k * 64 + f] = red[0][0][f] + red[0][1][f] + red[0][2][f] + red[0][3][f];
    } else if (t < 128) {
      pxsd[k * 64 + f] = red[1][0][f] + red[1][1][f] + red[1][2][f] + red[1][3][f];
    }
  }
  __threadfence();
  grid.sync();

  // ---- Phase 3: reduce partials, tiny u/v dots, epilogue stores ----
  if (t < 128) {
    int f = t & 63;
    const float* p = ((t < 64) ? pxd : pxsd) + (size_t)(b * 16) * 64 + f;
    float a = 0.f;
#pragma unroll
    for (int c = 0; c < 16; ++c) a += p[c * 64];
    uv[(t < 64) ? 0 : 1][f] = a;
  }
  __syncthreads();
  if (t < 128) {
    int o = t & 63;
    const float* src = uv[(t < 64) ? 0 : 1];
    float acc = 0.f;
#pragma unroll
    for (int f = 0; f < Fq; ++f) acc = fmaf(src[f], weight[f * Oq + o], acc);
    uv[(t < 64) ? 2 : 3][o] = acc;
  }
  __syncthreads();
  {
    int o0 = (t & 15) * 4;
    const float* u = uv[2];
    const float* v = uv[3];
#pragma unroll
    for (int pass = 0; pass < 16; ++pass) {
      int row = k * 256 + pass * 16 + (t >> 4);
      float sr = s_row[row];
      float di = rsqrtf(fmaxf(fmaf((float)Nq, sr + adj_b, scs), 1.0f));
      float a = di * (sr + adj_b);
      float4 r;
      r.x = fmaxf(0.f, fmaf(a, u[o0 + 0], fmaf(di, v[o0 + 0], bias[o0 + 0])));
      r.y = fmaxf(0.f, fmaf(a, u[o0 + 1], fmaf(di, v[o0 + 1], bias[o0 + 1])));
      r.z = fmaxf(0.f, fmaf(a, u[o0 + 2], fmaf(di, v[o0 + 2], bias[o0 + 2])));
      r.w = fmaxf(0.f, fmaf(a, u[o0 + 3], fmaf(di, v[o0 + 3], bias[o0 + 3])));
      reinterpret_cast<float4*>(out + (size_t)row * Oq)[t & 15] = r;
    }
  }
}

extern "C" void kernel_launch(void* const* d_in, const int* in_sizes, int n_in,
                              void* d_out, int out_size, void* d_ws,
                              size_t ws_size, hipStream_t stream) {
  const float* x = (const float*)d_in[0];       // (B,N,F)
  const float* adj_w = (const float*)d_in[1];   // (2F,)
  const float* adj_b = (const float*)d_in[2];   // scalar
  const float* weight = (const float*)d_in[3];  // (F,O)
  const float* bias = (const float*)d_in[4];    // (O,)
  float* out = (float*)d_out;                   // (B,N,O)
  float* ws = (float*)d_ws;

  void* args[] = {(void*)&x,      (void*)&adj_w, (void*)&adj_b, (void*)&weight,
                  (void*)&bias,   (void*)&out,   (void*)&ws};
  hipLaunchCooperativeKernel((void*)gcn_fused, dim3(64), dim3(256), args, 0,
                             stream);
}

// Round 4
// 73.485 us; speedup vs baseline: 1.6681x; 1.6681x over previous
//
#include <hip/hip_runtime.h>

// Problem constants (B, N, F, O) = (4, 4096, 64, 64)
#define Bq 4
#define Nq 4096
#define Fq 64
#define Oq 64

// Workspace float layout (no atomics, no init needed):
//   [0,     16384)  s_row     (B*N)
//   [16384, 32768)  s_col     (B*N)
//   [32768, 32832)  blocksum  (64)   per-K1-block partial sums of s_col (16/batch)
//   [32832, 41024)  pxd       (128 x 64) per-K2-block partials of xd
//   [41024, 49216)  pxsd      (128 x 64) per-K2-block partials of xsd

// K1: per-row dots s_col = x_row . adj_w[:F], s_row = x_row . adj_w[F:],
// plus per-block partial sum of s_col (256 rows/block, 16 blocks/batch).
__global__ __launch_bounds__(256) void k1_rowdots(
    const float* __restrict__ x, const float* __restrict__ adj_w,
    float* __restrict__ s_row, float* __restrict__ s_col,
    float* __restrict__ blocksum) {
  int r = blockIdx.x * 256 + threadIdx.x;  // 256 | 4096 -> block is batch-uniform
  const float4* xr = reinterpret_cast<const float4*>(x + (size_t)r * Fq);
  const float4* w0 = reinterpret_cast<const float4*>(adj_w);
  const float4* w1 = reinterpret_cast<const float4*>(adj_w + Fq);
  float sc = 0.f, sr = 0.f;
#pragma unroll
  for (int k = 0; k < Fq / 4; ++k) {
    float4 v = xr[k];
    float4 a = w0[k];
    float4 b = w1[k];
    sc += v.x * a.x + v.y * a.y + v.z * a.z + v.w * a.w;
    sr += v.x * b.x + v.y * b.y + v.z * b.z + v.w * b.w;
  }
  s_col[r] = sc;
  s_row[r] = sr;
  __shared__ float red[256];
  red[threadIdx.x] = sc;
  __syncthreads();
  for (int s = 128; s > 0; s >>= 1) {
    if (threadIdx.x < s) red[threadIdx.x] += red[threadIdx.x + s];
    __syncthreads();
  }
  if (threadIdx.x == 0) blocksum[blockIdx.x] = red[0];
}

// K2: per-block partials of xd[b,f] = sum_j d_j*x[b,j,f] and
// xsd[b,f] = sum_j s_col_j*d_j*x[b,j,f]. Grid B*32 blocks, 128 j's each.
// Thread (fq = t&15 -> f quad, jsub = t>>4): float4 x reads, 8 j-iters/thread.
__global__ __launch_bounds__(256) void k2_weighted(
    const float* __restrict__ x, const float* __restrict__ s_row,
    const float* __restrict__ s_col, const float* __restrict__ blocksum,
    const float* __restrict__ adj_bp, float* __restrict__ pxd,
    float* __restrict__ pxsd) {
  int b = blockIdx.x >> 5;
  int chunk = blockIdx.x & 31;
  int fq = threadIdx.x & 15;   // f quad index: covers f = 4*fq .. 4*fq+3
  int jsub = threadIdx.x >> 4; // 0..15
  const float adj_b = adj_bp[0];
  float scs = 0.f;
#pragma unroll
  for (int k = 0; k < 16; ++k) scs += blocksum[b * 16 + k];
  const int jcnt = Nq / 32;  // 128
  int j0 = chunk * jcnt;
  float4 axd = {0.f, 0.f, 0.f, 0.f};
  float4 axsd = {0.f, 0.f, 0.f, 0.f};
  for (int j = j0 + jsub; j < j0 + jcnt; j += 16) {
    int row = b * Nq + j;
    float srj = s_row[row];
    float scj = s_col[row];
    float dj = rsqrtf(fmaxf(fmaf((float)Nq, srj + adj_b, scs), 1.0f));
    float sdj = scj * dj;
    float4 xv = reinterpret_cast<const float4*>(x + (size_t)row * Fq)[fq];
    axd.x = fmaf(dj, xv.x, axd.x);
    axd.y = fmaf(dj, xv.y, axd.y);
    axd.z = fmaf(dj, xv.z, axd.z);
    axd.w = fmaf(dj, xv.w, axd.w);
    axsd.x = fmaf(sdj, xv.x, axsd.x);
    axsd.y = fmaf(sdj, xv.y, axsd.y);
    axsd.z = fmaf(sdj, xv.z, axsd.z);
    axsd.w = fmaf(sdj, xv.w, axsd.w);
  }
  __shared__ float red[2][16][64];
  *reinterpret_cast<float4*>(&red[0][jsub][fq * 4]) = axd;
  *reinterpret_cast<float4*>(&red[1][jsub][fq * 4]) = axsd;
  __syncthreads();
  int t = threadIdx.x;
  if (t < 64) {
    float s = 0.f;
#pragma unroll
    for (int c = 0; c < 16; ++c) s += red[0][c][t];
    pxd[blockIdx.x * 64 + t] = s;
  } else if (t < 128) {
    int f = t & 63;
    float s = 0.f;
#pragma unroll
    for (int c = 0; c < 16; ++c) s += red[1][c][f];
    pxsd[blockIdx.x * 64 + f] = s;
  }
}

// K3: reduce the 32 xd/xsd partials, compute u[o] = xd.W[:,o], v[o] = xsd.W[:,o]
// in LDS, then out[b,i,o] = relu(d_i*((s_row_i+adj_b)*u[o] + v[o]) + bias[o]).
// Grid 256 blocks (64/batch), each writes 64 rows x 64 o via float4.
__global__ __launch_bounds__(256) void k3_out(
    const float* __restrict__ s_row, const float* __restrict__ blocksum,
    const float* __restrict__ adj_bp, const float* __restrict__ pxd,
    const float* __restrict__ pxsd, const float* __restrict__ weight,
    const float* __restrict__ bias, float* __restrict__ out) {
  int b = blockIdx.x >> 6;
  int ibase = (blockIdx.x & 63) << 6;  // 64 rows per block
  const float adj_b = adj_bp[0];
  float scs = 0.f;
#pragma unroll
  for (int k = 0; k < 16; ++k) scs += blocksum[b * 16 + k];
  __shared__ float xdl[64], xsdl[64], u[64], v[64];
  int t = threadIdx.x;
  if (t < 128) {
    int f = t & 63;
    const float* p = ((t < 64) ? pxd : pxsd) + (size_t)(b * 32) * 64 + f;
    float a = 0.f;
#pragma unroll
    for (int c = 0; c < 32; ++c) a += p[c * 64];
    if (t < 64)
      xdl[f] = a;
    else
      xsdl[f] = a;
  }
  __syncthreads();
  if (t < 128) {
    int o = t & 63;
    const float* src = (t < 64) ? xdl : xsdl;
    float acc = 0.f;
#pragma unroll
    for (int f = 0; f < Fq; ++f) acc = fmaf(src[f], weight[f * Oq + o], acc);
    if (t < 64)
      u[o] = acc;
    else
      v[o] = acc;
  }
  __syncthreads();
  int o0 = (t & 15) * 4;
#pragma unroll
  for (int pass = 0; pass < 4; ++pass) {
    int row = ibase + pass * 16 + (t >> 4);
    int rg = b * Nq + row;
    float sr = s_row[rg];
    float rowsum = fmaf((float)Nq, sr + adj_b, scs);
    float di = rsqrtf(fmaxf(rowsum, 1.0f));
    float a = di * (sr + adj_b);
    float4 r;
    r.x = fmaxf(0.f, fmaf(a, u[o0 + 0], fmaf(di, v[o0 + 0], bias[o0 + 0])));
    r.y = fmaxf(0.f, fmaf(a, u[o0 + 1], fmaf(di, v[o0 + 1], bias[o0 + 1])));
    r.z = fmaxf(0.f, fmaf(a, u[o0 + 2], fmaf(di, v[o0 + 2], bias[o0 + 2])));
    r.w = fmaxf(0.f, fmaf(a, u[o0 + 3], fmaf(di, v[o0 + 3], bias[o0 + 3])));
    reinterpret_cast<float4*>(out + (size_t)rg * Oq)[t & 15] = r;
  }
}

extern "C" void kernel_launch(void* const* d_in, const int* in_sizes, int n_in,
                              void* d_out, int out_size, void* d_ws,
                              size_t ws_size, hipStream_t stream) {
  const float* x = (const float*)d_in[0];       // (B,N,F)
  const float* adj_w = (const float*)d_in[1];   // (2F,)
  const float* adj_b = (const float*)d_in[2];   // scalar
  const float* weight = (const float*)d_in[3];  // (F,O)
  const float* bias = (const float*)d_in[4];    // (O,)
  float* out = (float*)d_out;                   // (B,N,O)

  float* ws = (float*)d_ws;
  float* s_row = ws;
  float* s_col = ws + Bq * Nq;
  float* blocksum = ws + 2 * Bq * Nq;
  float* pxd = blocksum + 64;
  float* pxsd = pxd + 128 * 64;

  k1_rowdots<<<64, 256, 0, stream>>>(x, adj_w, s_row, s_col, blocksum);
  k2_weighted<<<Bq * 32, 256, 0, stream>>>(x, s_row, s_col, blocksum, adj_b,
                                           pxd, pxsd);
  k3_out<<<256, 256, 0, stream>>>(s_row, blocksum, adj_b, pxd, pxsd, weight,
                                  bias, out);
}